// Round 8
// baseline (237.005 us; speedup 1.0000x reference)
//
#include <hip/hip_runtime.h>
#include <hip/hip_fp16.h>

#define N_NODES 100000
#define N_EDGES 1600000
#define HIDDEN  128
#define N_CLASS 26

#define BUK_SHIFT 9
#define BUK_DSTS  512
#define NBUK      196            // ceil(100000/512)
#define BUK_CAP   10240          // avg 8163, wide headroom
#define PB_EDGES  8192
#define PB_BLOCKS ((N_EDGES + PB_EDGES - 1) / PB_EDGES)   // 196

typedef _Float16 f16x2 __attribute__((ext_vector_type(2)));

__device__ __forceinline__ float fdot2(__half2 a, __half2 b, float c) {
#if __has_builtin(__builtin_amdgcn_fdot2)
    union { __half2 h; f16x2 v; } ua, ub;
    ua.h = a; ub.h = b;
    return __builtin_amdgcn_fdot2(ua.v, ub.v, c, false);
#else
    float2 fa = __half22float2(a), fb = __half22float2(b);
    return c + fa.x * fb.x + fa.y * fb.y;
#endif
}

union U4 { uint4 u; __half2 h[4]; };
union U2 { uint2 u; __half2 h[2]; };
union UW { int i; __half2 h; };

// ---------------- pass B: bucket edges by dst>>9 with coalesced run writes ----------------

__global__ __launch_bounds__(1024) void bucket_kernel(const int* __restrict__ row,
                                                      const int* __restrict__ col,
                                                      const float* __restrict__ ew,
                                                      int* __restrict__ bukcnt,
                                                      int2* __restrict__ stage) {
    __shared__ int2 outst[PB_EDGES];            // 64 KB
    __shared__ unsigned short bukof[PB_EDGES];  // 16 KB
    __shared__ int cnt[NBUK], ofs[NBUK], cur[NBUK], gt[NBUK];
    __shared__ int sc[256];
    const int tid = threadIdx.x;
    const int e0 = blockIdx.x * PB_EDGES;
    const int nvalid = min(PB_EDGES, N_EDGES - e0);

    for (int b = tid; b < NBUK; b += 1024) { cnt[b] = 0; cur[b] = 0; }
    __syncthreads();

    int mykey[8]; float myw[8]; int mybuk[8];
#pragma unroll
    for (int i = 0; i < 8; ++i) {
        int idx = tid + i * 1024;                 // coalesced
        mybuk[i] = -1;
        if (idx < nvalid) {
            int e = e0 + idx;
            int d = col[e], r = row[e];
            int buk = d >> BUK_SHIFT;
            mykey[i] = ((d & (BUK_DSTS - 1)) << 17) | r;
            myw[i] = ew[e];
            mybuk[i] = buk;
            atomicAdd(&cnt[buk], 1);
        }
    }
    __syncthreads();

    // exclusive scan cnt[196] -> ofs
    {
        int c = (tid < NBUK) ? cnt[tid] : 0;
        if (tid < 256) sc[tid] = c;
        __syncthreads();
        for (int o = 1; o < 256; o <<= 1) {
            int v = 0;
            if (tid < 256 && tid >= o) v = sc[tid - o];
            __syncthreads();
            if (tid < 256) sc[tid] += v;
            __syncthreads();
        }
        if (tid < NBUK) ofs[tid] = sc[tid] - c;
        __syncthreads();
    }

#pragma unroll
    for (int i = 0; i < 8; ++i) {
        if (mybuk[i] >= 0) {
            int s = ofs[mybuk[i]] + atomicAdd(&cur[mybuk[i]], 1);
            outst[s] = make_int2(mykey[i], __float_as_int(myw[i]));
            bukof[s] = (unsigned short)mybuk[i];
        }
    }
    __syncthreads();

    if (tid < NBUK) {
        int c = cnt[tid];
        int gb = (c > 0) ? atomicAdd(&bukcnt[tid], c) : 0;
        gt[tid] = tid * BUK_CAP + gb;
    }
    __syncthreads();

    for (int i = tid; i < nvalid; i += 1024) {
        int b = bukof[i];
        stage[(size_t)gt[b] + (i - ofs[b])] = outst[i];
    }
}

// ---------------- scan bucket totals -> compact CSR bases ----------------

__global__ void bukscan_kernel(const int* __restrict__ bukcnt, int* __restrict__ bukbase,
                               int* __restrict__ start) {
    __shared__ int s[256];
    int tid = threadIdx.x;
    int c = (tid < NBUK) ? bukcnt[tid] : 0;
    s[tid] = c;
    __syncthreads();
    for (int o = 1; o < 256; o <<= 1) {
        int v = (tid >= o) ? s[tid - o] : 0;
        __syncthreads();
        s[tid] += v;
        __syncthreads();
    }
    if (tid < NBUK) bukbase[tid] = s[tid] - c;
    if (tid == 0) start[N_NODES] = N_EDGES;
}

// ---------------- pass C: per-bucket CSR + dinv + x16 + degree-sorted perm ----------------

__global__ __launch_bounds__(1024) void csr_kernel(const int2* __restrict__ stage,
                                                   const int* __restrict__ bukcnt,
                                                   const int* __restrict__ bukbase,
                                                   const float* __restrict__ x,
                                                   int* __restrict__ start,
                                                   float* __restrict__ dinv,
                                                   __half* __restrict__ x16,
                                                   int2* __restrict__ packed,
                                                   int* __restrict__ perm) {
    __shared__ unsigned int cnt5[BUK_DSTS];
    __shared__ int ofs5[BUK_DSTS];
    __shared__ unsigned int cur5[BUK_DSTS];
    __shared__ float deg5[BUK_DSTS];
    __shared__ float dv5[BUK_DSTS];
    __shared__ int sc[BUK_DSTS];
    __shared__ int dhist[128];
    __shared__ int dcur[128];
    const int tid = threadIdx.x;
    const int b = blockIdx.x;
    const int total = bukcnt[b];
    const int base = bukbase[b];
    const int2* st = stage + (size_t)b * BUK_CAP;

    for (int j = tid; j < BUK_DSTS; j += 1024) { cnt5[j] = 0; cur5[j] = 0; deg5[j] = 0.0f; }
    if (tid < 128) { dhist[tid] = 0; dcur[tid] = 0; }
    __syncthreads();

    for (int i = tid; i < total; i += 1024) {
        int2 en = st[i];
        int dl = en.x >> 17;
        atomicAdd(&cnt5[dl], 1u);
        atomicAdd(&deg5[dl], __int_as_float(en.y));
    }
    __syncthreads();

    // exclusive scan cnt5[512] -> ofs5
    {
        int c = (tid < BUK_DSTS) ? (int)cnt5[tid] : 0;
        if (tid < BUK_DSTS) sc[tid] = c;
        __syncthreads();
        for (int o = 1; o < BUK_DSTS; o <<= 1) {
            int v = 0;
            if (tid < BUK_DSTS && tid >= o) v = sc[tid - o];
            __syncthreads();
            if (tid < BUK_DSTS) sc[tid] += v;
            __syncthreads();
        }
        if (tid < BUK_DSTS) ofs5[tid] = sc[tid] - c;
        __syncthreads();
    }

    // degree histogram for within-bucket counting sort
    int myd = -1;
    {
        int d = (b << BUK_SHIFT) + tid;
        if (tid < BUK_DSTS && d < N_NODES) {
            myd = min((int)cnt5[tid], 127);
            atomicAdd(&dhist[myd], 1);
        }
    }

    if (tid < BUK_DSTS) {
        int d = (b << BUK_SHIFT) + tid;
        if (d < N_NODES) {
            float dv = rsqrtf(deg5[tid] + 1.0f);    // +1 self-loop
            dv5[tid] = dv;
            dinv[d] = dv;
            start[d] = base + ofs5[tid];
        }
    }
    __syncthreads();

    // scan dhist[128] -> ranks; perm[bucket_base + rank] = node
    if (tid < 128) sc[tid] = dhist[tid];
    __syncthreads();
    for (int o = 1; o < 128; o <<= 1) {
        int v = 0;
        if (tid < 128 && tid >= o) v = sc[tid - o];
        __syncthreads();
        if (tid < 128) sc[tid] += v;
        __syncthreads();
    }
    if (myd >= 0) {
        int rank = sc[myd] - dhist[myd] + atomicAdd(&dcur[myd], 1);
        perm[(b << BUK_SHIFT) + rank] = (b << BUK_SHIFT) + tid;
    }

    // x16 rows (prescaled by dinv, padded to 32) for this bucket's nodes
    for (int t = tid; t < BUK_DSTS * 32; t += 1024) {
        int j = t >> 5, l = t & 31;
        int d = (b << BUK_SHIFT) + j;
        if (d < N_NODES) {
            float v = (l < N_CLASS) ? x[(size_t)d * N_CLASS + l] * dv5[j] : 0.0f;
            x16[((size_t)d << 5) + l] = __float2half(v);
        }
    }

    // scatter into compact CSR region (L2-local), w packed as half2
    for (int i = tid; i < total; i += 1024) {
        int2 en = st[i];
        int dl = en.x >> 17;
        int src = en.x & 0x1FFFF;
        unsigned int r = atomicAdd(&cur5[dl], 1u);
        unsigned int hw = __half_as_ushort(__float2half(__int_as_float(en.y)));
        packed[(size_t)base + ofs5[dl] + (int)r] = make_int2(src, (int)(hw | (hw << 16)));
    }
}

// ---------------- layer1 (fused): gather26 + gemmB ----------------
// Phase 1: 8 lanes/node gather 32 perm-ordered nodes into LDS (fp32), unroll 8.
// Phase 2: 256 threads GEMM 32x26 @ 26x128, bias+relu, write h16.

__global__ __launch_bounds__(256) void layer1_kernel(const __half* __restrict__ x16,
                                                     const int* __restrict__ start,
                                                     const int2* __restrict__ packed,
                                                     const float* __restrict__ dinv,
                                                     const int* __restrict__ perm,
                                                     const float* __restrict__ W1,
                                                     const float* __restrict__ b1,
                                                     __half* __restrict__ h16) {
    __shared__ float axs[32][32];
    __shared__ int gl[32];
    const int tid = threadIdx.x;
    const int nb = blockIdx.x * 32;   // 3125*32 == 100000
    {
        const int j = tid >> 3;
        const int l = tid & 7;
        const int g = perm[nb + j];
        if (l == 0) gl[j] = g;
        const uint2* X = reinterpret_cast<const uint2*>(x16); // row = 8 uint2
        U2 sv; sv.u = X[((size_t)g << 3) + l];
        __half2 acc0 = sv.h[0], acc1 = sv.h[1];               // self-loop, ew=1
        int s = start[g], t = start[g + 1];
        int i = s;
        for (; i + 8 <= t; i += 8) {
            int2 pk[8]; U2 vv[8];
#pragma unroll
            for (int u = 0; u < 8; ++u) pk[u] = packed[i + u];
#pragma unroll
            for (int u = 0; u < 8; ++u) vv[u].u = X[((size_t)pk[u].x << 3) + l];
#pragma unroll
            for (int u = 0; u < 8; ++u) {
                UW w; w.i = pk[u].y;
                acc0 = __hfma2(w.h, vv[u].h[0], acc0);
                acc1 = __hfma2(w.h, vv[u].h[1], acc1);
            }
        }
        for (; i < t; ++i) {
            int2 p = packed[i];
            U2 v; v.u = X[((size_t)p.x << 3) + l];
            UW w; w.i = p.y;
            acc0 = __hfma2(w.h, v.h[0], acc0); acc1 = __hfma2(w.h, v.h[1], acc1);
        }
        float dg = dinv[g];
        float2 a = __half22float2(acc0), bb = __half22float2(acc1);
        *reinterpret_cast<float4*>(&axs[j][l * 4]) =
            make_float4(dg * a.x, dg * a.y, dg * bb.x, dg * bb.y);
    }
    __syncthreads();
    const int c = tid & 127;
    const int half = tid >> 7;
    float w[N_CLASS];
#pragma unroll
    for (int k = 0; k < N_CLASS; ++k) w[k] = W1[k * HIDDEN + c];
    const float bias = b1[c];
#pragma unroll
    for (int tt = 0; tt < 16; ++tt) {
        int n = half + 2 * tt;
        float acc = bias;
#pragma unroll
        for (int k = 0; k < N_CLASS; ++k) acc += axs[n][k] * w[k];
        h16[(size_t)gl[n] * HIDDEN + c] = __float2half(fmaxf(acc, 0.0f));
    }
}

// ---------------- gemmC: p16 = fp16(dinv * (h16 @ W2)) via fdot2 ----------------

#define CB_NODES 128
__global__ __launch_bounds__(512) void gemmC_kernel(const __half* __restrict__ h16,
                                                    const float* __restrict__ W2,
                                                    const float* __restrict__ dinv,
                                                    __half* __restrict__ p16) {
    __shared__ __half2 hs2[CB_NODES][HIDDEN / 2];   // 32 KB  [node][k2]
    __shared__ __half2 ws2[HIDDEN / 2][HIDDEN];     // 32 KB  [k2][c]
    const int tid = threadIdx.x;
    const int nb = blockIdx.x * CB_NODES;
    for (int t = tid; t < HIDDEN / 2 * HIDDEN; t += 512) {
        int k2 = t >> 7, c = t & 127;
        ws2[k2][c] = __floats2half2_rn(W2[(2 * k2) * HIDDEN + c], W2[(2 * k2 + 1) * HIDDEN + c]);
    }
    for (int t = tid; t < CB_NODES * 16; t += 512) {   // 16 uint4 per row
        int node = nb + (t >> 4);
        reinterpret_cast<uint4*>(hs2)[t] =
            (node < N_NODES)
                ? reinterpret_cast<const uint4*>(h16)[(size_t)node * 16 + (t & 15)]
                : make_uint4(0u, 0u, 0u, 0u);
    }
    __syncthreads();
    const int c4 = (tid & 31) * 4;
    const int n0 = (tid >> 5) * 8;
    float acc[8][4] = {};
    for (int k2 = 0; k2 < HIDDEN / 2; k2 += 2) {
        U4 wa, wb;
        wa.u = *reinterpret_cast<const uint4*>(&ws2[k2][c4]);
        wb.u = *reinterpret_cast<const uint4*>(&ws2[k2 + 1][c4]);
#pragma unroll
        for (int i = 0; i < 8; ++i) {
            U2 hv; hv.u = *reinterpret_cast<const uint2*>(&hs2[n0 + i][k2]);
#pragma unroll
            for (int q = 0; q < 4; ++q) {
                acc[i][q] = fdot2(hv.h[0], wa.h[q], acc[i][q]);
                acc[i][q] = fdot2(hv.h[1], wb.h[q], acc[i][q]);
            }
        }
    }
#pragma unroll
    for (int i = 0; i < 8; ++i) {
        int node = nb + n0 + i;
        if (node < N_NODES) {
            float d = dinv[node];
            union { __half2 h2[2]; uint2 u; } pk;
            pk.h2[0] = __floats2half2_rn(d * acc[i][0], d * acc[i][1]);
            pk.h2[1] = __floats2half2_rn(d * acc[i][2], d * acc[i][3]);
            *reinterpret_cast<uint2*>(&p16[(size_t)node * HIDDEN + c4]) = pk.u;
        }
    }
}

// ---------------- agg2: z16 = fp16(relu(dinv*(p16[g] + sum ew*p16[src]) + b2)) ----------------
// 16 lanes/node, perm-ordered, unroll 8, no LDS, no FC tail.

__global__ __launch_bounds__(256) void agg2_kernel(const __half* __restrict__ p16,
                                                   const int* __restrict__ start,
                                                   const int2* __restrict__ packed,
                                                   const float* __restrict__ dinv,
                                                   const int* __restrict__ perm,
                                                   const float* __restrict__ b2,
                                                   __half* __restrict__ z16) {
    const int grp = threadIdx.x >> 4;
    const int l   = threadIdx.x & 15;
    const int g   = perm[blockIdx.x * 16 + grp];    // 6250*16 == 100000
    const uint4* P = reinterpret_cast<const uint4*>(p16);   // row = 16 uint4

    U4 sv; sv.u = P[((size_t)g << 4) + l];          // self-loop, ew=1
    __half2 acc0 = sv.h[0], acc1 = sv.h[1], acc2 = sv.h[2], acc3 = sv.h[3];

    int s = start[g], t = start[g + 1];
    int i = s;
    for (; i + 8 <= t; i += 8) {
        int2 pk[8]; U4 vv[8];
#pragma unroll
        for (int u = 0; u < 8; ++u) pk[u] = packed[i + u];
#pragma unroll
        for (int u = 0; u < 8; ++u) vv[u].u = P[((size_t)pk[u].x << 4) + l];
#pragma unroll
        for (int u = 0; u < 8; ++u) {
            UW w; w.i = pk[u].y;
            acc0 = __hfma2(w.h, vv[u].h[0], acc0);
            acc1 = __hfma2(w.h, vv[u].h[1], acc1);
            acc2 = __hfma2(w.h, vv[u].h[2], acc2);
            acc3 = __hfma2(w.h, vv[u].h[3], acc3);
        }
    }
    for (; i + 4 <= t; i += 4) {
        int2 pk[4]; U4 vv[4];
#pragma unroll
        for (int u = 0; u < 4; ++u) pk[u] = packed[i + u];
#pragma unroll
        for (int u = 0; u < 4; ++u) vv[u].u = P[((size_t)pk[u].x << 4) + l];
#pragma unroll
        for (int u = 0; u < 4; ++u) {
            UW w; w.i = pk[u].y;
            acc0 = __hfma2(w.h, vv[u].h[0], acc0);
            acc1 = __hfma2(w.h, vv[u].h[1], acc1);
            acc2 = __hfma2(w.h, vv[u].h[2], acc2);
            acc3 = __hfma2(w.h, vv[u].h[3], acc3);
        }
    }
    for (; i < t; ++i) {
        int2 p = packed[i];
        U4 v; v.u = P[((size_t)p.x << 4) + l];
        UW w; w.i = p.y;
        acc0 = __hfma2(w.h, v.h[0], acc0); acc1 = __hfma2(w.h, v.h[1], acc1);
        acc2 = __hfma2(w.h, v.h[2], acc2); acc3 = __hfma2(w.h, v.h[3], acc3);
    }

    const float dg = dinv[g];
    const int f = l * 8;
    float4 ba = *reinterpret_cast<const float4*>(&b2[f]);
    float4 bb = *reinterpret_cast<const float4*>(&b2[f + 4]);
    float2 f0 = __half22float2(acc0), f1 = __half22float2(acc1);
    float2 f2 = __half22float2(acc2), f3 = __half22float2(acc3);
    U4 zz;
    zz.h[0] = __floats2half2_rn(fmaxf(dg * f0.x + ba.x, 0.f), fmaxf(dg * f0.y + ba.y, 0.f));
    zz.h[1] = __floats2half2_rn(fmaxf(dg * f1.x + ba.z, 0.f), fmaxf(dg * f1.y + ba.w, 0.f));
    zz.h[2] = __floats2half2_rn(fmaxf(dg * f2.x + bb.x, 0.f), fmaxf(dg * f2.y + bb.y, 0.f));
    zz.h[3] = __floats2half2_rn(fmaxf(dg * f3.x + bb.z, 0.f), fmaxf(dg * f3.y + bb.w, 0.f));
    reinterpret_cast<uint4*>(z16)[((size_t)g << 4) + l] = zz.u;
}

// ---------------- fc: out = z16 @ Wfc + bfc   [N,128]x[128,26] ----------------
// 128 nodes/block, 256 threads; Wfc column in 64 half2 regs; z tile in padded LDS.

#define FC_NODES 128
__global__ __launch_bounds__(256) void fc_kernel(const __half* __restrict__ z16,
                                                 const float* __restrict__ Wfc,
                                                 const float* __restrict__ bfc,
                                                 float* __restrict__ out) {
    __shared__ __align__(16) __half2 zsh[FC_NODES][68];   // stride 272 B: conflict-free
    const int tid = threadIdx.x;
    const int nb = blockIdx.x * FC_NODES;
    for (int t = tid; t < FC_NODES * 16; t += 256) {
        int n = t >> 4, q = t & 15;
        int node = nb + n;
        uint4 v = (node < N_NODES)
                      ? reinterpret_cast<const uint4*>(z16)[(size_t)node * 16 + q]
                      : make_uint4(0u, 0u, 0u, 0u);
        *reinterpret_cast<uint4*>(&zsh[n][q * 4]) = v;
    }
    const int j = tid & 31;
    const int slice = tid >> 5;          // 8 slices
    __half2 wreg[HIDDEN / 2];
    float bj = 0.0f;
    if (j < N_CLASS) {
        bj = bfc[j];
#pragma unroll
        for (int k2 = 0; k2 < HIDDEN / 2; ++k2)
            wreg[k2] = __floats2half2_rn(Wfc[(2 * k2) * N_CLASS + j],
                                         Wfc[(2 * k2 + 1) * N_CLASS + j]);
    }
    __syncthreads();
    if (j >= N_CLASS) return;
    for (int n = slice; n < FC_NODES; n += 8) {
        int node = nb + n;
        if (node < N_NODES) {
            float acc = bj;
#pragma unroll
            for (int k2 = 0; k2 < HIDDEN / 2; ++k2)
                acc = fdot2(zsh[n][k2], wreg[k2], acc);
            out[(size_t)node * N_CLASS + j] = acc;
        }
    }
}

// ---------------- launch ----------------

extern "C" void kernel_launch(void* const* d_in, const int* in_sizes, int n_in,
                              void* d_out, int out_size, void* d_ws, size_t ws_size,
                              hipStream_t stream) {
    const float* x   = (const float*)d_in[0];
    const int*   ei  = (const int*)  d_in[1];
    const float* ew  = (const float*)d_in[2];
    const float* W1  = (const float*)d_in[3];
    const float* b1  = (const float*)d_in[4];
    const float* W2  = (const float*)d_in[5];
    const float* b2  = (const float*)d_in[6];
    const float* Wfc = (const float*)d_in[7];
    const float* bfc = (const float*)d_in[8];
    float* out = (float*)d_out;

    const int n = N_NODES, E = N_EDGES;
    const int* row = ei;
    const int* col = ei + E;

    char* ws = (char*)d_ws;
    size_t off = 0;
    auto alloc = [&](size_t bytes) -> void* {
        void* ptr = ws + off;
        off += (bytes + 255) & ~(size_t)255;
        return ptr;
    };
    int*   bukcnt  = (int*)  alloc(NBUK * 4);
    int*   bukbase = (int*)  alloc(NBUK * 4);
    float* dinv    = (float*)alloc((size_t)n * 4);
    int*   start   = (int*)  alloc((size_t)(n + 1) * 4);
    int*   perm    = (int*)  alloc((size_t)n * 4);
    int2*  packed  = (int2*) alloc((size_t)E * 8);
    __half* x16    = (__half*)alloc((size_t)n * 32 * 2);
    __half* h16    = (__half*)alloc((size_t)n * HIDDEN * 2 < (size_t)NBUK * BUK_CAP * 8
                                        ? (size_t)NBUK * BUK_CAP * 8
                                        : (size_t)n * HIDDEN * 2);
    __half* p16    = (__half*)alloc((size_t)n * HIDDEN * 2);
    int2*  stage   = (int2*)h16;   // alias: stage (16 MB) dead before layer1 writes h16
    __half* z16    = h16;          // alias: h16 dead after gemmC; agg2 writes z16 after

    hipMemsetAsync(bukcnt, 0, NBUK * 4, stream);
    bucket_kernel<<<PB_BLOCKS, 1024, 0, stream>>>(row, col, ew, bukcnt, stage);
    bukscan_kernel<<<1, 256, 0, stream>>>(bukcnt, bukbase, start);
    csr_kernel<<<NBUK, 1024, 0, stream>>>(stage, bukcnt, bukbase, x, start, dinv, x16, packed, perm);

    // layer 1 (fused gather + GEMM)
    layer1_kernel<<<(n + 31) / 32, 256, 0, stream>>>(x16, start, packed, dinv, perm, W1, b1, h16);

    // layer 2
    gemmC_kernel<<<(n + CB_NODES - 1) / CB_NODES, 512, 0, stream>>>(h16, W2, dinv, p16);
    agg2_kernel<<<(n + 15) / 16, 256, 0, stream>>>(p16, start, packed, dinv, perm, b2, z16);

    // final FC
    fc_kernel<<<(n + FC_NODES - 1) / FC_NODES, 256, 0, stream>>>(z16, Wfc, bfc, out);
}

// Round 9
// 223.953 us; speedup vs baseline: 1.0583x; 1.0583x over previous
//
#include <hip/hip_runtime.h>
#include <hip/hip_fp16.h>

#define N_NODES 100000
#define N_EDGES 1600000
#define HIDDEN  128
#define N_CLASS 26

#define BUK_SHIFT 8
#define BUK_DSTS  256
#define NBUK      391            // ceil(100000/256)
#define BUK_CAP   5120           // avg 4092, wide headroom
#define PB_EDGES  4096
#define PB_BLOCKS ((N_EDGES + PB_EDGES - 1) / PB_EDGES)   // 391

typedef _Float16 f16x2 __attribute__((ext_vector_type(2)));

__device__ __forceinline__ float fdot2(__half2 a, __half2 b, float c) {
#if __has_builtin(__builtin_amdgcn_fdot2)
    union { __half2 h; f16x2 v; } ua, ub;
    ua.h = a; ub.h = b;
    return __builtin_amdgcn_fdot2(ua.v, ub.v, c, false);
#else
    float2 fa = __half22float2(a), fb = __half22float2(b);
    return c + fa.x * fb.x + fa.y * fb.y;
#endif
}

union U4 { uint4 u; __half2 h[4]; };
union U2 { uint2 u; __half2 h[2]; };
union UW { int i; __half2 h; };

// ---------------- pass B: bucket edges by dst>>8, coalesced run writes ----------------
// 512 threads, 8 edges/thread; 391 blocks.

__global__ __launch_bounds__(512) void bucket_kernel(const int* __restrict__ row,
                                                     const int* __restrict__ col,
                                                     const float* __restrict__ ew,
                                                     int* __restrict__ bukcnt,
                                                     int2* __restrict__ stage) {
    __shared__ int2 outst[PB_EDGES];            // 32 KB
    __shared__ unsigned short bukof[PB_EDGES];  // 8 KB
    __shared__ int cnt[NBUK], ofs[NBUK], cur[NBUK], gt[NBUK];   // ~6.3 KB
    __shared__ int sc[512];
    const int tid = threadIdx.x;
    const int e0 = blockIdx.x * PB_EDGES;
    const int nvalid = min(PB_EDGES, N_EDGES - e0);

    for (int b = tid; b < NBUK; b += 512) { cnt[b] = 0; cur[b] = 0; }
    __syncthreads();

    int mykey[8]; float myw[8]; int mybuk[8];
#pragma unroll
    for (int i = 0; i < 8; ++i) {
        int idx = tid + i * 512;                  // coalesced
        mybuk[i] = -1;
        if (idx < nvalid) {
            int e = e0 + idx;
            int d = col[e], r = row[e];
            int buk = d >> BUK_SHIFT;
            mykey[i] = ((d & (BUK_DSTS - 1)) << 17) | r;
            myw[i] = ew[e];
            mybuk[i] = buk;
            atomicAdd(&cnt[buk], 1);
        }
    }
    __syncthreads();

    // exclusive scan cnt[391] -> ofs (512-wide Hillis-Steele)
    {
        int c = (tid < NBUK) ? cnt[tid] : 0;
        sc[tid] = c;
        __syncthreads();
        for (int o = 1; o < 512; o <<= 1) {
            int v = (tid >= o) ? sc[tid - o] : 0;
            __syncthreads();
            sc[tid] += v;
            __syncthreads();
        }
        if (tid < NBUK) ofs[tid] = sc[tid] - c;
        __syncthreads();
    }

#pragma unroll
    for (int i = 0; i < 8; ++i) {
        if (mybuk[i] >= 0) {
            int s = ofs[mybuk[i]] + atomicAdd(&cur[mybuk[i]], 1);
            outst[s] = make_int2(mykey[i], __float_as_int(myw[i]));
            bukof[s] = (unsigned short)mybuk[i];
        }
    }
    __syncthreads();

    if (tid < NBUK) {
        int c = cnt[tid];
        int gb = (c > 0) ? atomicAdd(&bukcnt[tid], c) : 0;
        gt[tid] = tid * BUK_CAP + gb;
    }
    __syncthreads();

    // coalesced flush: consecutive i -> consecutive addresses within each run
    for (int i = tid; i < nvalid; i += 512) {
        int b = bukof[i];
        stage[(size_t)gt[b] + (i - ofs[b])] = outst[i];
    }
}

// ---------------- scan bucket totals -> compact CSR bases ----------------

__global__ void bukscan_kernel(const int* __restrict__ bukcnt, int* __restrict__ bukbase,
                               int* __restrict__ start) {
    __shared__ int s[512];
    int tid = threadIdx.x;
    int c = (tid < NBUK) ? bukcnt[tid] : 0;
    s[tid] = c;
    __syncthreads();
    for (int o = 1; o < 512; o <<= 1) {
        int v = (tid >= o) ? s[tid - o] : 0;
        __syncthreads();
        s[tid] += v;
        __syncthreads();
    }
    if (tid < NBUK) bukbase[tid] = s[tid] - c;
    if (tid == 0) start[N_NODES] = N_EDGES;
}

// ---------------- pass C: per-bucket CSR + dinv + x16 + degree-sorted perm ----------------
// 391 blocks x 1024 threads, one 256-dst bucket each.

__global__ __launch_bounds__(1024) void csr_kernel(const int2* __restrict__ stage,
                                                   const int* __restrict__ bukcnt,
                                                   const int* __restrict__ bukbase,
                                                   const float* __restrict__ x,
                                                   int* __restrict__ start,
                                                   float* __restrict__ dinv,
                                                   __half* __restrict__ x16,
                                                   int2* __restrict__ packed,
                                                   int* __restrict__ perm) {
    __shared__ unsigned int cnt5[BUK_DSTS];
    __shared__ int ofs5[BUK_DSTS];
    __shared__ unsigned int cur5[BUK_DSTS];
    __shared__ float deg5[BUK_DSTS];
    __shared__ float dv5[BUK_DSTS];
    __shared__ int sc[BUK_DSTS];
    __shared__ int dhist[128];
    __shared__ int dcur[128];
    const int tid = threadIdx.x;
    const int b = blockIdx.x;
    const int total = bukcnt[b];
    const int base = bukbase[b];
    const int2* st = stage + (size_t)b * BUK_CAP;

    if (tid < BUK_DSTS) { cnt5[tid] = 0; cur5[tid] = 0; deg5[tid] = 0.0f; }
    if (tid < 128) { dhist[tid] = 0; dcur[tid] = 0; }
    __syncthreads();

    for (int i = tid; i < total; i += 1024) {
        int2 en = st[i];
        int dl = en.x >> 17;
        atomicAdd(&cnt5[dl], 1u);
        atomicAdd(&deg5[dl], __int_as_float(en.y));
    }
    __syncthreads();

    // exclusive scan cnt5[256] -> ofs5
    {
        int c = (tid < BUK_DSTS) ? (int)cnt5[tid] : 0;
        if (tid < BUK_DSTS) sc[tid] = c;
        __syncthreads();
        for (int o = 1; o < BUK_DSTS; o <<= 1) {
            int v = 0;
            if (tid < BUK_DSTS && tid >= o) v = sc[tid - o];
            __syncthreads();
            if (tid < BUK_DSTS) sc[tid] += v;
            __syncthreads();
        }
        if (tid < BUK_DSTS) ofs5[tid] = sc[tid] - c;
        __syncthreads();
    }

    // degree histogram for within-bucket counting sort
    int myd = -1;
    {
        int d = (b << BUK_SHIFT) + tid;
        if (tid < BUK_DSTS && d < N_NODES) {
            myd = min((int)cnt5[tid], 127);
            atomicAdd(&dhist[myd], 1);
        }
    }

    if (tid < BUK_DSTS) {
        int d = (b << BUK_SHIFT) + tid;
        if (d < N_NODES) {
            float dv = rsqrtf(deg5[tid] + 1.0f);    // +1 self-loop
            dv5[tid] = dv;
            dinv[d] = dv;
            start[d] = base + ofs5[tid];
        }
    }
    __syncthreads();

    // scan dhist[128] -> ranks; perm[bucket_base + rank] = node
    if (tid < 128) sc[tid] = dhist[tid];
    __syncthreads();
    for (int o = 1; o < 128; o <<= 1) {
        int v = 0;
        if (tid < 128 && tid >= o) v = sc[tid - o];
        __syncthreads();
        if (tid < 128) sc[tid] += v;
        __syncthreads();
    }
    if (myd >= 0) {
        int rank = sc[myd] - dhist[myd] + atomicAdd(&dcur[myd], 1);
        perm[(b << BUK_SHIFT) + rank] = (b << BUK_SHIFT) + tid;
    }

    // x16 rows (prescaled by dinv, padded to 32)
    for (int t = tid; t < BUK_DSTS * 32; t += 1024) {
        int j = t >> 5, l = t & 31;
        int d = (b << BUK_SHIFT) + j;
        if (d < N_NODES) {
            float v = (l < N_CLASS) ? x[(size_t)d * N_CLASS + l] * dv5[j] : 0.0f;
            x16[((size_t)d << 5) + l] = __float2half(v);
        }
    }

    // scatter into compact CSR region (L2-local), w packed as half2
    for (int i = tid; i < total; i += 1024) {
        int2 en = st[i];
        int dl = en.x >> 17;
        int src = en.x & 0x1FFFF;
        unsigned int r = atomicAdd(&cur5[dl], 1u);
        unsigned int hw = __half_as_ushort(__float2half(__int_as_float(en.y)));
        packed[(size_t)base + ofs5[dl] + (int)r] = make_int2(src, (int)(hw | (hw << 16)));
    }
}

// ---------------- layer1 (fused): gather26 + gemmB ----------------

__global__ __launch_bounds__(256) void layer1_kernel(const __half* __restrict__ x16,
                                                     const int* __restrict__ start,
                                                     const int2* __restrict__ packed,
                                                     const float* __restrict__ dinv,
                                                     const int* __restrict__ perm,
                                                     const float* __restrict__ W1,
                                                     const float* __restrict__ b1,
                                                     __half* __restrict__ h16) {
    __shared__ float axs[32][32];
    __shared__ int gl[32];
    const int tid = threadIdx.x;
    const int nb = blockIdx.x * 32;   // 3125*32 == 100000
    {
        const int j = tid >> 3;
        const int l = tid & 7;
        const int g = perm[nb + j];
        if (l == 0) gl[j] = g;
        const uint2* X = reinterpret_cast<const uint2*>(x16); // row = 8 uint2
        U2 sv; sv.u = X[((size_t)g << 3) + l];
        __half2 acc0 = sv.h[0], acc1 = sv.h[1];               // self-loop, ew=1
        int s = start[g], t = start[g + 1];
        int i = s;
        for (; i + 8 <= t; i += 8) {
            int2 pk[8]; U2 vv[8];
#pragma unroll
            for (int u = 0; u < 8; ++u) pk[u] = packed[i + u];
#pragma unroll
            for (int u = 0; u < 8; ++u) vv[u].u = X[((size_t)pk[u].x << 3) + l];
#pragma unroll
            for (int u = 0; u < 8; ++u) {
                UW w; w.i = pk[u].y;
                acc0 = __hfma2(w.h, vv[u].h[0], acc0);
                acc1 = __hfma2(w.h, vv[u].h[1], acc1);
            }
        }
        for (; i < t; ++i) {
            int2 p = packed[i];
            U2 v; v.u = X[((size_t)p.x << 3) + l];
            UW w; w.i = p.y;
            acc0 = __hfma2(w.h, v.h[0], acc0); acc1 = __hfma2(w.h, v.h[1], acc1);
        }
        float dg = dinv[g];
        float2 a = __half22float2(acc0), bb = __half22float2(acc1);
        *reinterpret_cast<float4*>(&axs[j][l * 4]) =
            make_float4(dg * a.x, dg * a.y, dg * bb.x, dg * bb.y);
    }
    __syncthreads();
    const int c = tid & 127;
    const int half = tid >> 7;
    float w[N_CLASS];
#pragma unroll
    for (int k = 0; k < N_CLASS; ++k) w[k] = W1[k * HIDDEN + c];
    const float bias = b1[c];
#pragma unroll
    for (int tt = 0; tt < 16; ++tt) {
        int n = half + 2 * tt;
        float acc = bias;
#pragma unroll
        for (int k = 0; k < N_CLASS; ++k) acc += axs[n][k] * w[k];
        h16[(size_t)gl[n] * HIDDEN + c] = __float2half(fmaxf(acc, 0.0f));
    }
}

// ---------------- gemmC: p16 = fp16(dinv * (h16 @ W2)) via fdot2 ----------------

#define CB_NODES 128
__global__ __launch_bounds__(512) void gemmC_kernel(const __half* __restrict__ h16,
                                                    const float* __restrict__ W2,
                                                    const float* __restrict__ dinv,
                                                    __half* __restrict__ p16) {
    __shared__ __half2 hs2[CB_NODES][HIDDEN / 2];   // 32 KB  [node][k2]
    __shared__ __half2 ws2[HIDDEN / 2][HIDDEN];     // 32 KB  [k2][c]
    const int tid = threadIdx.x;
    const int nb = blockIdx.x * CB_NODES;
    for (int t = tid; t < HIDDEN / 2 * HIDDEN; t += 512) {
        int k2 = t >> 7, c = t & 127;
        ws2[k2][c] = __floats2half2_rn(W2[(2 * k2) * HIDDEN + c], W2[(2 * k2 + 1) * HIDDEN + c]);
    }
    for (int t = tid; t < CB_NODES * 16; t += 512) {   // 16 uint4 per row
        int node = nb + (t >> 4);
        reinterpret_cast<uint4*>(hs2)[t] =
            (node < N_NODES)
                ? reinterpret_cast<const uint4*>(h16)[(size_t)node * 16 + (t & 15)]
                : make_uint4(0u, 0u, 0u, 0u);
    }
    __syncthreads();
    const int c4 = (tid & 31) * 4;
    const int n0 = (tid >> 5) * 8;
    float acc[8][4] = {};
    for (int k2 = 0; k2 < HIDDEN / 2; k2 += 2) {
        U4 wa, wb;
        wa.u = *reinterpret_cast<const uint4*>(&ws2[k2][c4]);
        wb.u = *reinterpret_cast<const uint4*>(&ws2[k2 + 1][c4]);
#pragma unroll
        for (int i = 0; i < 8; ++i) {
            U2 hv; hv.u = *reinterpret_cast<const uint2*>(&hs2[n0 + i][k2]);
#pragma unroll
            for (int q = 0; q < 4; ++q) {
                acc[i][q] = fdot2(hv.h[0], wa.h[q], acc[i][q]);
                acc[i][q] = fdot2(hv.h[1], wb.h[q], acc[i][q]);
            }
        }
    }
#pragma unroll
    for (int i = 0; i < 8; ++i) {
        int node = nb + n0 + i;
        if (node < N_NODES) {
            float d = dinv[node];
            union { __half2 h2[2]; uint2 u; } pk;
            pk.h2[0] = __floats2half2_rn(d * acc[i][0], d * acc[i][1]);
            pk.h2[1] = __floats2half2_rn(d * acc[i][2], d * acc[i][3]);
            *reinterpret_cast<uint2*>(&p16[(size_t)node * HIDDEN + c4]) = pk.u;
        }
    }
}

// ---------------- aggfc (fused): out = relu(dinv*(p16[g]+sum ew*p16[src])+b2) @ Wfc + bfc ----------------
// 16 lanes/node, perm-ordered, unroll 8, padded zs2, fdot2 FC tail.

__global__ __launch_bounds__(256) void aggfc_kernel(const __half* __restrict__ p16,
                                                    const int* __restrict__ start,
                                                    const int2* __restrict__ packed,
                                                    const float* __restrict__ dinv,
                                                    const int* __restrict__ perm,
                                                    const float* __restrict__ b2,
                                                    const float* __restrict__ Wfc,
                                                    const float* __restrict__ bfc,
                                                    float* __restrict__ out) {
    __shared__ __half2 wf2[HIDDEN / 2][N_CLASS];   // [k2][j]
    __shared__ float bfs[N_CLASS];
    __shared__ __half2 zs2[16][65];                // pad 65: conflict-free across groups
    const int tid = threadIdx.x;
    for (int t = tid; t < HIDDEN / 2 * N_CLASS; t += 256) {
        int k2 = t / N_CLASS, j = t % N_CLASS;
        wf2[k2][j] = __floats2half2_rn(Wfc[(2 * k2) * N_CLASS + j], Wfc[(2 * k2 + 1) * N_CLASS + j]);
    }
    if (tid < N_CLASS) bfs[tid] = bfc[tid];
    __syncthreads();

    const int grp = tid >> 4;
    const int l   = tid & 15;
    const int g   = perm[blockIdx.x * 16 + grp];    // 6250*16 == 100000
    const uint4* P = reinterpret_cast<const uint4*>(p16);   // row = 16 uint4

    U4 sv; sv.u = P[((size_t)g << 4) + l];          // self-loop, ew=1
    __half2 acc0 = sv.h[0], acc1 = sv.h[1], acc2 = sv.h[2], acc3 = sv.h[3];

    int s = start[g], t = start[g + 1];
    int i = s;
    for (; i + 8 <= t; i += 8) {
        int2 pk[8]; U4 vv[8];
#pragma unroll
        for (int u = 0; u < 8; ++u) pk[u] = packed[i + u];
#pragma unroll
        for (int u = 0; u < 8; ++u) vv[u].u = P[((size_t)pk[u].x << 4) + l];
#pragma unroll
        for (int u = 0; u < 8; ++u) {
            UW w; w.i = pk[u].y;
            acc0 = __hfma2(w.h, vv[u].h[0], acc0);
            acc1 = __hfma2(w.h, vv[u].h[1], acc1);
            acc2 = __hfma2(w.h, vv[u].h[2], acc2);
            acc3 = __hfma2(w.h, vv[u].h[3], acc3);
        }
    }
    for (; i + 4 <= t; i += 4) {
        int2 pk[4]; U4 vv[4];
#pragma unroll
        for (int u = 0; u < 4; ++u) pk[u] = packed[i + u];
#pragma unroll
        for (int u = 0; u < 4; ++u) vv[u].u = P[((size_t)pk[u].x << 4) + l];
#pragma unroll
        for (int u = 0; u < 4; ++u) {
            UW w; w.i = pk[u].y;
            acc0 = __hfma2(w.h, vv[u].h[0], acc0);
            acc1 = __hfma2(w.h, vv[u].h[1], acc1);
            acc2 = __hfma2(w.h, vv[u].h[2], acc2);
            acc3 = __hfma2(w.h, vv[u].h[3], acc3);
        }
    }
    for (; i < t; ++i) {
        int2 p = packed[i];
        U4 v; v.u = P[((size_t)p.x << 4) + l];
        UW w; w.i = p.y;
        acc0 = __hfma2(w.h, v.h[0], acc0); acc1 = __hfma2(w.h, v.h[1], acc1);
        acc2 = __hfma2(w.h, v.h[2], acc2); acc3 = __hfma2(w.h, v.h[3], acc3);
    }

    const float dg = dinv[g];
    const int f = l * 8;
    float4 ba = *reinterpret_cast<const float4*>(&b2[f]);
    float4 bb = *reinterpret_cast<const float4*>(&b2[f + 4]);
    float2 f0 = __half22float2(acc0), f1 = __half22float2(acc1);
    float2 f2 = __half22float2(acc2), f3 = __half22float2(acc3);
    zs2[grp][l * 4 + 0] = __floats2half2_rn(fmaxf(dg * f0.x + ba.x, 0.f), fmaxf(dg * f0.y + ba.y, 0.f));
    zs2[grp][l * 4 + 1] = __floats2half2_rn(fmaxf(dg * f1.x + ba.z, 0.f), fmaxf(dg * f1.y + ba.w, 0.f));
    zs2[grp][l * 4 + 2] = __floats2half2_rn(fmaxf(dg * f2.x + bb.x, 0.f), fmaxf(dg * f2.y + bb.y, 0.f));
    zs2[grp][l * 4 + 3] = __floats2half2_rn(fmaxf(dg * f3.x + bb.z, 0.f), fmaxf(dg * f3.y + bb.w, 0.f));
    // 16-lane group lives in one wave: lockstep, no barrier needed for zs2 reuse.
#pragma unroll
    for (int jj = l; jj < N_CLASS; jj += 16) {
        float accf = bfs[jj];
#pragma unroll 16
        for (int k2 = 0; k2 < HIDDEN / 2; ++k2)
            accf = fdot2(zs2[grp][k2], wf2[k2][jj], accf);
        out[(size_t)g * N_CLASS + jj] = accf;
    }
}

// ---------------- launch ----------------

extern "C" void kernel_launch(void* const* d_in, const int* in_sizes, int n_in,
                              void* d_out, int out_size, void* d_ws, size_t ws_size,
                              hipStream_t stream) {
    const float* x   = (const float*)d_in[0];
    const int*   ei  = (const int*)  d_in[1];
    const float* ew  = (const float*)d_in[2];
    const float* W1  = (const float*)d_in[3];
    const float* b1  = (const float*)d_in[4];
    const float* W2  = (const float*)d_in[5];
    const float* b2  = (const float*)d_in[6];
    const float* Wfc = (const float*)d_in[7];
    const float* bfc = (const float*)d_in[8];
    float* out = (float*)d_out;

    const int n = N_NODES, E = N_EDGES;
    const int* row = ei;
    const int* col = ei + E;

    char* ws = (char*)d_ws;
    size_t off = 0;
    auto alloc = [&](size_t bytes) -> void* {
        void* ptr = ws + off;
        off += (bytes + 255) & ~(size_t)255;
        return ptr;
    };
    int*   bukcnt  = (int*)  alloc(NBUK * 4);
    int*   bukbase = (int*)  alloc(NBUK * 4);
    float* dinv    = (float*)alloc((size_t)n * 4);
    int*   start   = (int*)  alloc((size_t)(n + 1) * 4);
    int*   perm    = (int*)  alloc((size_t)n * 4);
    int2*  packed  = (int2*) alloc((size_t)E * 8);
    __half* x16    = (__half*)alloc((size_t)n * 32 * 2);
    __half* h16    = (__half*)alloc((size_t)n * HIDDEN * 2 < (size_t)NBUK * BUK_CAP * 8
                                        ? (size_t)NBUK * BUK_CAP * 8
                                        : (size_t)n * HIDDEN * 2);
    __half* p16    = (__half*)alloc((size_t)n * HIDDEN * 2);
    int2*  stage   = (int2*)h16;   // alias: stage (16 MB) dead before layer1 writes h16

    hipMemsetAsync(bukcnt, 0, NBUK * 4, stream);
    bucket_kernel<<<PB_BLOCKS, 512, 0, stream>>>(row, col, ew, bukcnt, stage);
    bukscan_kernel<<<1, 512, 0, stream>>>(bukcnt, bukbase, start);
    csr_kernel<<<NBUK, 1024, 0, stream>>>(stage, bukcnt, bukbase, x, start, dinv, x16, packed, perm);

    // layer 1 (fused gather + GEMM)
    layer1_kernel<<<(n + 31) / 32, 256, 0, stream>>>(x16, start, packed, dinv, perm, W1, b1, h16);

    // layer 2 + FC (fused)
    gemmC_kernel<<<(n + CB_NODES - 1) / CB_NODES, 512, 0, stream>>>(h16, W2, dinv, p16);
    aggfc_kernel<<<(n + 15) / 16, 256, 0, stream>>>(p16, start, packed, dinv, perm, b2, Wfc, bfc, out);
}

// Round 10
// 218.835 us; speedup vs baseline: 1.0830x; 1.0234x over previous
//
#include <hip/hip_runtime.h>
#include <hip/hip_fp16.h>

#define N_NODES 100000
#define N_EDGES 1600000
#define HIDDEN  128
#define N_CLASS 26

#define BUK_SHIFT 8
#define BUK_DSTS  256
#define NBUK      391            // ceil(100000/256)
#define BUK_CAP   5120           // avg 4092, 16-sigma headroom
#define PB_EDGES  4096
#define PB_BLOCKS ((N_EDGES + PB_EDGES - 1) / PB_EDGES)   // 391

typedef _Float16 f16x2 __attribute__((ext_vector_type(2)));

__device__ __forceinline__ float fdot2(__half2 a, __half2 b, float c) {
#if __has_builtin(__builtin_amdgcn_fdot2)
    union { __half2 h; f16x2 v; } ua, ub;
    ua.h = a; ub.h = b;
    return __builtin_amdgcn_fdot2(ua.v, ub.v, c, false);
#else
    float2 fa = __half22float2(a), fb = __half22float2(b);
    return c + fa.x * fb.x + fa.y * fb.y;
#endif
}

union U4 { uint4 u; __half2 h[4]; };
union U2 { uint2 u; __half2 h[2]; };
union UW { int i; __half2 h; };

// wave-level inclusive scan (64 lanes, no barriers)
__device__ __forceinline__ int wave_iscan(int v, int lane) {
#pragma unroll
    for (int o = 1; o < 64; o <<= 1) {
        int u = __shfl_up(v, o, 64);
        if (lane >= o) v += u;
    }
    return v;
}

// ---------------- pass B: bucket edges by dst>>8, coalesced run writes ----------------
// 512 threads, 8 edges/thread, 391 blocks; shuffle-scan (2 barriers).

__global__ __launch_bounds__(512) void bucket_kernel(const int* __restrict__ row,
                                                     const int* __restrict__ col,
                                                     const float* __restrict__ ew,
                                                     int* __restrict__ bukcnt,
                                                     int2* __restrict__ stage) {
    __shared__ int2 outst[PB_EDGES];            // 32 KB
    __shared__ unsigned short bukof[PB_EDGES];  // 8 KB
    __shared__ int cnt[NBUK], ofs[NBUK], cur[NBUK], gt[NBUK];   // ~6.3 KB
    __shared__ int wsum[8], woff[8];
    const int tid = threadIdx.x;
    const int lane = tid & 63;
    const int wid = tid >> 6;
    const int e0 = blockIdx.x * PB_EDGES;
    const int nvalid = min(PB_EDGES, N_EDGES - e0);

    for (int b = tid; b < NBUK; b += 512) { cnt[b] = 0; cur[b] = 0; }
    __syncthreads();

    int mykey[8]; float myw[8]; int mybuk[8];
#pragma unroll
    for (int i = 0; i < 8; ++i) {
        int idx = tid + i * 512;                  // coalesced
        mybuk[i] = -1;
        if (idx < nvalid) {
            int e = e0 + idx;
            int d = col[e], r = row[e];
            int buk = d >> BUK_SHIFT;
            mykey[i] = ((d & (BUK_DSTS - 1)) << 17) | r;
            myw[i] = ew[e];
            mybuk[i] = buk;
            atomicAdd(&cnt[buk], 1);
        }
    }
    __syncthreads();

    // exclusive scan cnt[391] -> ofs via wave shuffles (2 barriers)
    {
        int c = (tid < NBUK) ? cnt[tid] : 0;
        int sv = wave_iscan(c, lane);
        if (lane == 63) wsum[wid] = sv;
        __syncthreads();
        if (tid < 8) {
            int acc = 0;
            for (int k = 0; k < tid; ++k) acc += wsum[k];
            woff[tid] = acc;
        }
        __syncthreads();
        if (tid < NBUK) ofs[tid] = sv - c + woff[wid];
        __syncthreads();
    }

#pragma unroll
    for (int i = 0; i < 8; ++i) {
        if (mybuk[i] >= 0) {
            int s = ofs[mybuk[i]] + atomicAdd(&cur[mybuk[i]], 1);
            outst[s] = make_int2(mykey[i], __float_as_int(myw[i]));
            bukof[s] = (unsigned short)mybuk[i];
        }
    }
    __syncthreads();

    if (tid < NBUK) {
        int c = cnt[tid];
        int gb = (c > 0) ? atomicAdd(&bukcnt[tid], c) : 0;
        gt[tid] = tid * BUK_CAP + gb;
    }
    __syncthreads();

    // coalesced flush: consecutive i -> consecutive addresses within each run
    for (int i = tid; i < nvalid; i += 512) {
        int b = bukof[i];
        stage[(size_t)gt[b] + (i - ofs[b])] = outst[i];
    }
}

// ---------------- scan bucket totals -> compact CSR bases ----------------

__global__ __launch_bounds__(512) void bukscan_kernel(const int* __restrict__ bukcnt,
                                                      int* __restrict__ bukbase,
                                                      int* __restrict__ start) {
    __shared__ int wsum[8], woff[8];
    const int tid = threadIdx.x;
    const int lane = tid & 63;
    const int wid = tid >> 6;
    int c = (tid < NBUK) ? bukcnt[tid] : 0;
    int sv = wave_iscan(c, lane);
    if (lane == 63) wsum[wid] = sv;
    __syncthreads();
    if (tid < 8) {
        int acc = 0;
        for (int k = 0; k < tid; ++k) acc += wsum[k];
        woff[tid] = acc;
    }
    __syncthreads();
    if (tid < NBUK) bukbase[tid] = sv - c + woff[wid];
    if (tid == 0) start[N_NODES] = N_EDGES;
}

// ---------------- pass C: per-bucket CSR + dinv + x16 + degree-sorted perm ----------------
// 391 blocks x 512 threads; single pass over stage (registers), shuffle scans.

__global__ __launch_bounds__(512) void csr_kernel(const int2* __restrict__ stage,
                                                  const int* __restrict__ bukcnt,
                                                  const int* __restrict__ bukbase,
                                                  const float* __restrict__ x,
                                                  int* __restrict__ start,
                                                  float* __restrict__ dinv,
                                                  __half* __restrict__ x16,
                                                  int2* __restrict__ packed,
                                                  int* __restrict__ perm) {
    __shared__ unsigned int cnt5[BUK_DSTS];
    __shared__ int ofs5[BUK_DSTS];
    __shared__ unsigned int cur5[BUK_DSTS];
    __shared__ float deg5[BUK_DSTS];
    __shared__ float dv5[BUK_DSTS];
    __shared__ int dhist[128], dcur[128], hofs[128];
    __shared__ int wsum[8], woff[8];
    const int tid = threadIdx.x;
    const int lane = tid & 63;
    const int wid = tid >> 6;
    const int b = blockIdx.x;
    const int total = bukcnt[b];
    const int base = bukbase[b];
    const int2* st = stage + (size_t)b * BUK_CAP;

    if (tid < BUK_DSTS) { cnt5[tid] = 0; cur5[tid] = 0; deg5[tid] = 0.0f; }
    if (tid < 128) { dhist[tid] = 0; dcur[tid] = 0; }
    __syncthreads();

    // single pass: load entries to registers, count
    int2 en[10];
    int nmine = 0;
#pragma unroll
    for (int k = 0; k < 10; ++k) {
        int idx = tid + k * 512;
        if (idx < total) {
            en[k] = st[idx];
            int dl = en[k].x >> 17;
            atomicAdd(&cnt5[dl], 1u);
            atomicAdd(&deg5[dl], __int_as_float(en[k].y));
            nmine = k + 1;
        }
    }
    __syncthreads();

    // exclusive scan cnt5[256] -> ofs5 (waves 0-3)
    {
        int c = (tid < BUK_DSTS) ? (int)cnt5[tid] : 0;
        int sv = wave_iscan(c, lane);
        if (lane == 63 && wid < 4) wsum[wid] = sv;
        __syncthreads();
        if (tid < 4) {
            int acc = 0;
            for (int k = 0; k < tid; ++k) acc += wsum[k];
            woff[tid] = acc;
        }
        __syncthreads();
        if (tid < BUK_DSTS) ofs5[tid] = sv - c + woff[wid];
    }

    // degree histogram + dinv + start
    int myd = -1;
    if (tid < BUK_DSTS) {
        int d = (b << BUK_SHIFT) + tid;
        if (d < N_NODES) {
            myd = min((int)cnt5[tid], 127);
            atomicAdd(&dhist[myd], 1);
            float dv = rsqrtf(deg5[tid] + 1.0f);    // +1 self-loop
            dv5[tid] = dv;
            dinv[d] = dv;
            start[d] = base + ofs5[tid];
        }
    }
    __syncthreads();

    // exclusive scan dhist[128] -> hofs (waves 0-1)
    {
        int c = (tid < 128) ? dhist[tid] : 0;
        int sv = wave_iscan(c, lane);
        if (lane == 63 && wid < 2) wsum[wid] = sv;
        __syncthreads();
        if (tid < 128) hofs[tid] = sv - c + ((wid == 1) ? wsum[0] : 0);
        __syncthreads();
    }
    if (myd >= 0) {
        int rank = hofs[myd] + atomicAdd(&dcur[myd], 1);
        perm[(b << BUK_SHIFT) + rank] = (b << BUK_SHIFT) + tid;
    }

    // x16 rows (prescaled by dinv, padded to 32), half2 stores
    for (int t = tid; t < BUK_DSTS * 16; t += 512) {
        int j = t >> 4, p = t & 15;
        int d = (b << BUK_SHIFT) + j;
        if (d < N_NODES) {
            int l0 = 2 * p, l1 = 2 * p + 1;
            float dv = dv5[j];
            float v0 = (l0 < N_CLASS) ? x[(size_t)d * N_CLASS + l0] * dv : 0.0f;
            float v1 = (l1 < N_CLASS) ? x[(size_t)d * N_CLASS + l1] * dv : 0.0f;
            reinterpret_cast<__half2*>(x16)[((size_t)d << 4) + p] = __floats2half2_rn(v0, v1);
        }
    }

    // scatter from registers into compact CSR region (L2-local), w packed as half2
#pragma unroll
    for (int k = 0; k < 10; ++k) {
        if (k < nmine) {
            int dl = en[k].x >> 17;
            int src = en[k].x & 0x1FFFF;
            unsigned int r = atomicAdd(&cur5[dl], 1u);
            unsigned int hw = __half_as_ushort(__float2half(__int_as_float(en[k].y)));
            packed[(size_t)base + ofs5[dl] + (int)r] = make_int2(src, (int)(hw | (hw << 16)));
        }
    }
}

// ---------------- layer1 (fused): gather26 + gemmB ----------------

__global__ __launch_bounds__(256) void layer1_kernel(const __half* __restrict__ x16,
                                                     const int* __restrict__ start,
                                                     const int2* __restrict__ packed,
                                                     const float* __restrict__ dinv,
                                                     const int* __restrict__ perm,
                                                     const float* __restrict__ W1,
                                                     const float* __restrict__ b1,
                                                     __half* __restrict__ h16) {
    __shared__ float axs[32][32];
    __shared__ int gl[32];
    const int tid = threadIdx.x;
    const int nb = blockIdx.x * 32;   // 3125*32 == 100000
    {
        const int j = tid >> 3;
        const int l = tid & 7;
        const int g = perm[nb + j];
        if (l == 0) gl[j] = g;
        const uint2* X = reinterpret_cast<const uint2*>(x16); // row = 8 uint2
        U2 sv; sv.u = X[((size_t)g << 3) + l];
        __half2 acc0 = sv.h[0], acc1 = sv.h[1];               // self-loop, ew=1
        int s = start[g], t = start[g + 1];
        int i = s;
        for (; i + 8 <= t; i += 8) {
            int2 pk[8]; U2 vv[8];
#pragma unroll
            for (int u = 0; u < 8; ++u) pk[u] = packed[i + u];
#pragma unroll
            for (int u = 0; u < 8; ++u) vv[u].u = X[((size_t)pk[u].x << 3) + l];
#pragma unroll
            for (int u = 0; u < 8; ++u) {
                UW w; w.i = pk[u].y;
                acc0 = __hfma2(w.h, vv[u].h[0], acc0);
                acc1 = __hfma2(w.h, vv[u].h[1], acc1);
            }
        }
        for (; i < t; ++i) {
            int2 p = packed[i];
            U2 v; v.u = X[((size_t)p.x << 3) + l];
            UW w; w.i = p.y;
            acc0 = __hfma2(w.h, v.h[0], acc0); acc1 = __hfma2(w.h, v.h[1], acc1);
        }
        float dg = dinv[g];
        float2 a = __half22float2(acc0), bb = __half22float2(acc1);
        *reinterpret_cast<float4*>(&axs[j][l * 4]) =
            make_float4(dg * a.x, dg * a.y, dg * bb.x, dg * bb.y);
    }
    __syncthreads();
    const int c = tid & 127;
    const int half = tid >> 7;
    float w[N_CLASS];
#pragma unroll
    for (int k = 0; k < N_CLASS; ++k) w[k] = W1[k * HIDDEN + c];
    const float bias = b1[c];
#pragma unroll
    for (int tt = 0; tt < 16; ++tt) {
        int n = half + 2 * tt;
        float acc = bias;
#pragma unroll
        for (int k = 0; k < N_CLASS; ++k) acc += axs[n][k] * w[k];
        h16[(size_t)gl[n] * HIDDEN + c] = __float2half(fmaxf(acc, 0.0f));
    }
}

// ---------------- gemmC: p16 = fp16(dinv * (h16 @ W2)) via fdot2 ----------------

#define CB_NODES 128
__global__ __launch_bounds__(512) void gemmC_kernel(const __half* __restrict__ h16,
                                                    const float* __restrict__ W2,
                                                    const float* __restrict__ dinv,
                                                    __half* __restrict__ p16) {
    __shared__ __half2 hs2[CB_NODES][HIDDEN / 2];   // 32 KB  [node][k2]
    __shared__ __half2 ws2[HIDDEN / 2][HIDDEN];     // 32 KB  [k2][c]
    const int tid = threadIdx.x;
    const int nb = blockIdx.x * CB_NODES;
    for (int t = tid; t < HIDDEN / 2 * HIDDEN; t += 512) {
        int k2 = t >> 7, c = t & 127;
        ws2[k2][c] = __floats2half2_rn(W2[(2 * k2) * HIDDEN + c], W2[(2 * k2 + 1) * HIDDEN + c]);
    }
    for (int t = tid; t < CB_NODES * 16; t += 512) {   // 16 uint4 per row
        int node = nb + (t >> 4);
        reinterpret_cast<uint4*>(hs2)[t] =
            (node < N_NODES)
                ? reinterpret_cast<const uint4*>(h16)[(size_t)node * 16 + (t & 15)]
                : make_uint4(0u, 0u, 0u, 0u);
    }
    __syncthreads();
    const int c4 = (tid & 31) * 4;
    const int n0 = (tid >> 5) * 8;
    float acc[8][4] = {};
    for (int k2 = 0; k2 < HIDDEN / 2; k2 += 2) {
        U4 wa, wb;
        wa.u = *reinterpret_cast<const uint4*>(&ws2[k2][c4]);
        wb.u = *reinterpret_cast<const uint4*>(&ws2[k2 + 1][c4]);
#pragma unroll
        for (int i = 0; i < 8; ++i) {
            U2 hv; hv.u = *reinterpret_cast<const uint2*>(&hs2[n0 + i][k2]);
#pragma unroll
            for (int q = 0; q < 4; ++q) {
                acc[i][q] = fdot2(hv.h[0], wa.h[q], acc[i][q]);
                acc[i][q] = fdot2(hv.h[1], wb.h[q], acc[i][q]);
            }
        }
    }
#pragma unroll
    for (int i = 0; i < 8; ++i) {
        int node = nb + n0 + i;
        if (node < N_NODES) {
            float d = dinv[node];
            union { __half2 h2[2]; uint2 u; } pk;
            pk.h2[0] = __floats2half2_rn(d * acc[i][0], d * acc[i][1]);
            pk.h2[1] = __floats2half2_rn(d * acc[i][2], d * acc[i][3]);
            *reinterpret_cast<uint2*>(&p16[(size_t)node * HIDDEN + c4]) = pk.u;
        }
    }
}

// ---------------- aggfc (fused): out = relu(dinv*(p16[g]+sum ew*p16[src])+b2) @ Wfc + bfc ----------------
// 16 lanes/node, perm-ordered, unroll 4 (R7 config: 24 VGPR, high occupancy).

__global__ __launch_bounds__(256) void aggfc_kernel(const __half* __restrict__ p16,
                                                    const int* __restrict__ start,
                                                    const int2* __restrict__ packed,
                                                    const float* __restrict__ dinv,
                                                    const int* __restrict__ perm,
                                                    const float* __restrict__ b2,
                                                    const float* __restrict__ Wfc,
                                                    const float* __restrict__ bfc,
                                                    float* __restrict__ out) {
    __shared__ __half2 wf2[HIDDEN / 2][N_CLASS];   // [k2][j]
    __shared__ float bfs[N_CLASS];
    __shared__ __half2 zs2[16][65];                // pad 65: conflict-free across groups
    const int tid = threadIdx.x;
    for (int t = tid; t < HIDDEN / 2 * N_CLASS; t += 256) {
        int k2 = t / N_CLASS, j = t % N_CLASS;
        wf2[k2][j] = __floats2half2_rn(Wfc[(2 * k2) * N_CLASS + j], Wfc[(2 * k2 + 1) * N_CLASS + j]);
    }
    if (tid < N_CLASS) bfs[tid] = bfc[tid];
    __syncthreads();

    const int grp = tid >> 4;
    const int l   = tid & 15;
    const int g   = perm[blockIdx.x * 16 + grp];    // 6250*16 == 100000
    const uint4* P = reinterpret_cast<const uint4*>(p16);   // row = 16 uint4

    U4 sv; sv.u = P[((size_t)g << 4) + l];          // self-loop, ew=1
    __half2 acc0 = sv.h[0], acc1 = sv.h[1], acc2 = sv.h[2], acc3 = sv.h[3];

    int s = start[g], t = start[g + 1];
    int i = s;
    for (; i + 4 <= t; i += 4) {
        int2 pa = packed[i], pb = packed[i + 1], pc = packed[i + 2], pd = packed[i + 3];
        U4 va, vb, vc, vd;
        va.u = P[((size_t)pa.x << 4) + l];
        vb.u = P[((size_t)pb.x << 4) + l];
        vc.u = P[((size_t)pc.x << 4) + l];
        vd.u = P[((size_t)pd.x << 4) + l];
        UW wa, wb, wc, wd; wa.i = pa.y; wb.i = pb.y; wc.i = pc.y; wd.i = pd.y;
        acc0 = __hfma2(wa.h, va.h[0], acc0); acc1 = __hfma2(wa.h, va.h[1], acc1);
        acc2 = __hfma2(wa.h, va.h[2], acc2); acc3 = __hfma2(wa.h, va.h[3], acc3);
        acc0 = __hfma2(wb.h, vb.h[0], acc0); acc1 = __hfma2(wb.h, vb.h[1], acc1);
        acc2 = __hfma2(wb.h, vb.h[2], acc2); acc3 = __hfma2(wb.h, vb.h[3], acc3);
        acc0 = __hfma2(wc.h, vc.h[0], acc0); acc1 = __hfma2(wc.h, vc.h[1], acc1);
        acc2 = __hfma2(wc.h, vc.h[2], acc2); acc3 = __hfma2(wc.h, vc.h[3], acc3);
        acc0 = __hfma2(wd.h, vd.h[0], acc0); acc1 = __hfma2(wd.h, vd.h[1], acc1);
        acc2 = __hfma2(wd.h, vd.h[2], acc2); acc3 = __hfma2(wd.h, vd.h[3], acc3);
    }
    for (; i < t; ++i) {
        int2 p = packed[i];
        U4 v; v.u = P[((size_t)p.x << 4) + l];
        UW w; w.i = p.y;
        acc0 = __hfma2(w.h, v.h[0], acc0); acc1 = __hfma2(w.h, v.h[1], acc1);
        acc2 = __hfma2(w.h, v.h[2], acc2); acc3 = __hfma2(w.h, v.h[3], acc3);
    }

    const float dg = dinv[g];
    const int f = l * 8;
    float4 ba = *reinterpret_cast<const float4*>(&b2[f]);
    float4 bb = *reinterpret_cast<const float4*>(&b2[f + 4]);
    float2 f0 = __half22float2(acc0), f1 = __half22float2(acc1);
    float2 f2 = __half22float2(acc2), f3 = __half22float2(acc3);
    zs2[grp][l * 4 + 0] = __floats2half2_rn(fmaxf(dg * f0.x + ba.x, 0.f), fmaxf(dg * f0.y + ba.y, 0.f));
    zs2[grp][l * 4 + 1] = __floats2half2_rn(fmaxf(dg * f1.x + ba.z, 0.f), fmaxf(dg * f1.y + ba.w, 0.f));
    zs2[grp][l * 4 + 2] = __floats2half2_rn(fmaxf(dg * f2.x + bb.x, 0.f), fmaxf(dg * f2.y + bb.y, 0.f));
    zs2[grp][l * 4 + 3] = __floats2half2_rn(fmaxf(dg * f3.x + bb.z, 0.f), fmaxf(dg * f3.y + bb.w, 0.f));
    // 16-lane group lives in one wave: lockstep, no barrier needed for zs2 reuse.
#pragma unroll
    for (int jj = l; jj < N_CLASS; jj += 16) {
        float accf = bfs[jj];
#pragma unroll 16
        for (int k2 = 0; k2 < HIDDEN / 2; ++k2)
            accf = fdot2(zs2[grp][k2], wf2[k2][jj], accf);
        out[(size_t)g * N_CLASS + jj] = accf;
    }
}

// ---------------- launch ----------------

extern "C" void kernel_launch(void* const* d_in, const int* in_sizes, int n_in,
                              void* d_out, int out_size, void* d_ws, size_t ws_size,
                              hipStream_t stream) {
    const float* x   = (const float*)d_in[0];
    const int*   ei  = (const int*)  d_in[1];
    const float* ew  = (const float*)d_in[2];
    const float* W1  = (const float*)d_in[3];
    const float* b1  = (const float*)d_in[4];
    const float* W2  = (const float*)d_in[5];
    const float* b2  = (const float*)d_in[6];
    const float* Wfc = (const float*)d_in[7];
    const float* bfc = (const float*)d_in[8];
    float* out = (float*)d_out;

    const int n = N_NODES, E = N_EDGES;
    const int* row = ei;
    const int* col = ei + E;

    char* ws = (char*)d_ws;
    size_t off = 0;
    auto alloc = [&](size_t bytes) -> void* {
        void* ptr = ws + off;
        off += (bytes + 255) & ~(size_t)255;
        return ptr;
    };
    int*   bukcnt  = (int*)  alloc(NBUK * 4);
    int*   bukbase = (int*)  alloc(NBUK * 4);
    float* dinv    = (float*)alloc((size_t)n * 4);
    int*   start   = (int*)  alloc((size_t)(n + 1) * 4);
    int*   perm    = (int*)  alloc((size_t)n * 4);
    int2*  packed  = (int2*) alloc((size_t)E * 8);
    __half* x16    = (__half*)alloc((size_t)n * 32 * 2);
    __half* h16    = (__half*)alloc((size_t)n * HIDDEN * 2 < (size_t)NBUK * BUK_CAP * 8
                                        ? (size_t)NBUK * BUK_CAP * 8
                                        : (size_t)n * HIDDEN * 2);
    __half* p16    = (__half*)alloc((size_t)n * HIDDEN * 2);
    int2*  stage   = (int2*)h16;   // alias: stage dead before layer1 writes h16

    hipMemsetAsync(bukcnt, 0, NBUK * 4, stream);
    bucket_kernel<<<PB_BLOCKS, 512, 0, stream>>>(row, col, ew, bukcnt, stage);
    bukscan_kernel<<<1, 512, 0, stream>>>(bukcnt, bukbase, start);
    csr_kernel<<<NBUK, 512, 0, stream>>>(stage, bukcnt, bukbase, x, start, dinv, x16, packed, perm);

    // layer 1 (fused gather + GEMM)
    layer1_kernel<<<(n + 31) / 32, 256, 0, stream>>>(x16, start, packed, dinv, perm, W1, b1, h16);

    // layer 2 + FC (fused)
    gemmC_kernel<<<(n + CB_NODES - 1) / CB_NODES, 512, 0, stream>>>(h16, W2, dinv, p16);
    aggfc_kernel<<<(n + 15) / 16, 256, 0, stream>>>(p16, start, packed, dinv, perm, b2, Wfc, bfc, out);
}